// Round 4
// baseline (113.305 us; speedup 1.0000x reference)
//
#include <hip/hip_runtime.h>
#include <hip/hip_bf16.h>

// CriticHead fused, round 4: single kernel, B-fragments hoisted to registers.
//
// Math (verified R1 fp32 absmax 0; R2/R3 bf16 absmax 1.5 < 2.0):
//   feat[t] = [outer3(res,fr,estep)(150) | backbone(768)]  (W1 row order)
//   y2 = relu(feat @ W1 + b1);  y41 = y2*mean(enode);  y42 = y2*(sum ccl)(sum cnd)
//   heads -> y = (1-p)*(-100) + p*(y61+y62), p = sig(me*d3+b3)*sig(sc*d5+b5)
//
// R3 post-mortem: kernel ~39us. Cause: B loaded from global INSIDE the
// accumulator-dependent 29-chunk MFMA loop; at 2 waves/SIMD each chunk pays a
// near-full L2-under-contention round trip (~1000 cy, calibrated by R1's
// 1090 cy/iter). R4: each wave's 29 B-fragments (29 x uintx4 = 116 VGPR) are
// gathered from W1 ONCE before the staging barrier (independent loads,
// latency overlapped with bb staging + outer-product build). K-loop becomes
// pure ds_read_b128 + mfma. Same B values / RNE cvt / chunk order / head math
// as R2/R3 -> bitwise-identical output (absmax 1.5).

typedef __bf16  bf16x8 __attribute__((ext_vector_type(8)));
typedef float   f32x4  __attribute__((ext_vector_type(4)));
typedef unsigned int uintx4 __attribute__((ext_vector_type(4)));
typedef unsigned short ushort4e __attribute__((ext_vector_type(4)));

#define FAILC -100.0f
#define ASTRIDE 936         // LDS feat row stride in bf16 (16B-aligned rows)

static __device__ __forceinline__ unsigned short f2bf(float f) {
    unsigned u = __builtin_bit_cast(unsigned, f);
    u = (u + 0x7FFFu + ((u >> 16) & 1u)) >> 16;   // RNE
    return (unsigned short)u;
}

__global__ __launch_bounds__(512) void critic_fused(
    const float* __restrict__ bb,     // [T,768]
    const float* __restrict__ res,    // [T,5]
    const float* __restrict__ fr,     // [T,5]
    const float* __restrict__ estep,  // [T,6]
    const float* __restrict__ enode,  // [T,64]
    const float* __restrict__ ccl,    // [T,4]
    const float* __restrict__ cnd,    // [T,32]
    const float* __restrict__ W1,     // [918,128]
    const float* __restrict__ b1,     // [128]
    const float* __restrict__ W3, const float* __restrict__ b3,
    const float* __restrict__ W4, const float* __restrict__ b4,
    const float* __restrict__ W5, const float* __restrict__ b5,
    const float* __restrict__ W6, const float* __restrict__ b6,
    float* __restrict__ out)          // [T]
{
    __shared__ unsigned short a_lds[16 * ASTRIDE];  // bf16 feat, K-permuted
    __shared__ float s_y2[16][132];                 // relu(fc1) fp32
    __shared__ float s_small[16][16];               // res(5) fr(5) estep(6)

    const int t = threadIdx.x;
    const int task0 = blockIdx.x * 16;

    const int lane = t & 63;
    const int wave = t >> 6;
    const int mrow = lane & 15;
    const int quad = lane >> 4;
    const int ncol = wave * 16 + mrow;

    // ---- issue backbone loads FIRST (longest latency: HBM) ----
    const float4* bbp = (const float4*)(bb + (size_t)task0 * 768);
    float4 bbv[6];
#pragma unroll
    for (int it = 0; it < 6; ++it) bbv[it] = bbp[t + it * 512];

    // ---- stage small vectors ----
    if (t < 256) {
        int r = t >> 4, q = t & 15;
        int tg = task0 + r;
        float v;
        if (q < 5)       v = res[tg * 5 + q];
        else if (q < 10) v = fr[tg * 5 + (q - 5)];
        else             v = estep[tg * 6 + (q - 10)];
        s_small[r][q] = v;
    }

    // ---- hoisted B-fragment gather: 29 chunks x 8 scattered W1 dwords ----
    // frag j of chunk c: B[k=32c+quad*8+j][ncol]; permuted K: k<768 -> row
    // 150+k, 768<=k<918 -> row k-768, else 0. Per-c row base is compile-time
    // uniform after full unroll (768 = 24*32). Independent loads -> pipelined.
    uintx4 barr[29];
#pragma unroll
    for (int c = 0; c < 29; ++c) {
        const int kq0 = c * 32 + quad * 8;
        float fv[8];
#pragma unroll
        for (int j = 0; j < 8; ++j) {
            int k = kq0 + j;
            int row = (k < 768) ? (150 + k) : (k - 768);
            fv[j] = (k < 918) ? W1[(size_t)row * 128 + ncol] : 0.0f;
        }
        uintx4 bp;
        bp.x = (unsigned)f2bf(fv[0]) | ((unsigned)f2bf(fv[1]) << 16);
        bp.y = (unsigned)f2bf(fv[2]) | ((unsigned)f2bf(fv[3]) << 16);
        bp.z = (unsigned)f2bf(fv[4]) | ((unsigned)f2bf(fv[5]) << 16);
        bp.w = (unsigned)f2bf(fv[6]) | ((unsigned)f2bf(fv[7]) << 16);
        barr[c] = bp;
    }

    // ---- write backbone -> bf16 LDS cols [0,768) ----
#pragma unroll
    for (int it = 0; it < 6; ++it) {
        int i = t + it * 512;          // 0..3071
        int m = i / 192;               // task row
        int off = (i - m * 192) * 4;   // col in [0,768)
        float4 v = bbv[it];
        ushort4e pk = { f2bf(v.x), f2bf(v.y), f2bf(v.z), f2bf(v.w) };
        *(ushort4e*)&a_lds[m * ASTRIDE + off] = pk;
    }
    __syncthreads();

    // outer products -> cols [768,918); zero pad cols [918,928)
    for (int w = t; w < 2560; w += 512) {
        if (w < 2400) {
            int r = w / 150;
            int idx = w - r * 150;
            int n = idx / 30;
            int rem = idx - n * 30;
            int m = rem / 6;
            int o = rem - m * 6;
            float v = s_small[r][n] * s_small[r][5 + m] * s_small[r][10 + o];
            a_lds[r * ASTRIDE + 768 + idx] = f2bf(v);
        } else {
            int z = w - 2400;              // 0..159
            int r = z / 10;
            a_lds[r * ASTRIDE + 918 + (z - r * 10)] = 0;
        }
    }
    __syncthreads();

    // ---- MFMA loop: pure LDS + MFMA, B from registers ----
    const unsigned short* aptr = a_lds + mrow * ASTRIDE + quad * 8;

    f32x4 acc = {0.f, 0.f, 0.f, 0.f};
#pragma unroll
    for (int c = 0; c < 29; ++c) {
        uintx4 au = *(const uintx4*)(aptr + c * 32);
        acc = __builtin_amdgcn_mfma_f32_16x16x32_bf16(
            __builtin_bit_cast(bf16x8, au), __builtin_bit_cast(bf16x8, barr[c]),
            acc, 0, 0, 0);
    }

    // epilogue: bias + relu -> s_y2.  D layout: col=lane&15, row=quad*4+reg.
    {
        float bias = b1[ncol];
#pragma unroll
        for (int r = 0; r < 4; ++r) {
            int m = quad * 4 + r;
            s_y2[m][ncol] = fmaxf(acc[r] + bias, 0.f);
        }
    }
    __syncthreads();

    // ---- heads (identical math to R1/R2/R3) ----
    const int kq = t & 31;
    const int rsub = t >> 5;
    const int tg = task0 + rsub;
    const int k4 = kq * 4;

    float4 yv = *(const float4*)&s_y2[rsub][k4];
    float y0 = yv.x, y1 = yv.y, y2v = yv.z, y3 = yv.w;

    float4 w3v = *(const float4*)(W3 + k4);
    float4 w4v = *(const float4*)(W4 + k4);
    float4 w5v = *(const float4*)(W5 + k4);
    float4 w6v = *(const float4*)(W6 + k4);
    float pd3 = y0 * w3v.x + y1 * w3v.y + y2v * w3v.z + y3 * w3v.w;
    float pd4 = y0 * w4v.x + y1 * w4v.y + y2v * w4v.z + y3 * w4v.w;
    float pd5 = y0 * w5v.x + y1 * w5v.y + y2v * w5v.z + y3 * w5v.w;
    float pd6 = y0 * w6v.x + y1 * w6v.y + y2v * w6v.z + y3 * w6v.w;

    const float* en = enode + (size_t)tg * 64 + kq * 2;
    float pe = en[0] + en[1];
    float pc = (kq < 4) ? ccl[tg * 4 + kq] : 0.f;
    float pn = cnd[tg * 32 + kq];

#pragma unroll
    for (int m = 1; m < 32; m <<= 1) {
        pd3 += __shfl_xor(pd3, m);
        pd4 += __shfl_xor(pd4, m);
        pd5 += __shfl_xor(pd5, m);
        pd6 += __shfl_xor(pd6, m);
        pe  += __shfl_xor(pe, m);
        pc  += __shfl_xor(pc, m);
        pn  += __shfl_xor(pn, m);
    }

    if (kq == 0) {
        float me = pe * (1.0f / 64.0f);
        float sc = pc * pn;
        float a3 = me * pd3 + b3[0];
        float a5 = sc * pd5 + b5[0];
        float y51 = 1.0f / (1.0f + __expf(-a3));
        float y52 = 1.0f / (1.0f + __expf(-a5));
        float y61 = me * pd4 + b4[0];
        float y62 = sc * pd6 + b6[0];
        float p = y51 * y52;
        out[tg] = (1.0f - p) * FAILC + p * (y61 + y62);
    }
}

extern "C" void kernel_launch(void* const* d_in, const int* in_sizes, int n_in,
                              void* d_out, int out_size, void* d_ws, size_t ws_size,
                              hipStream_t stream) {
    const float* bb    = (const float*)d_in[2];
    const float* res   = (const float*)d_in[3];
    const float* fr    = (const float*)d_in[4];
    const float* estep = (const float*)d_in[5];
    const float* enode = (const float*)d_in[6];
    const float* ccl   = (const float*)d_in[7];
    const float* cnd   = (const float*)d_in[8];
    const float* W1    = (const float*)d_in[9];
    const float* b1    = (const float*)d_in[10];
    const float* W3    = (const float*)d_in[11];
    const float* b3    = (const float*)d_in[12];
    const float* W4    = (const float*)d_in[13];
    const float* b4    = (const float*)d_in[14];
    const float* W5    = (const float*)d_in[15];
    const float* b5    = (const float*)d_in[16];
    const float* W6    = (const float*)d_in[17];
    const float* b6    = (const float*)d_in[18];
    float* out = (float*)d_out;

    int T = in_sizes[3] / 5;      // y_res is [T,5]
    int blocks = T / 16;          // 16 tasks per block

    hipLaunchKernelGGL(critic_fused, dim3(blocks), dim3(512), 0, stream,
                       bb, res, fr, estep, enode, ccl, cnd,
                       W1, b1, W3, b3, W4, b4, W5, b5, W6, b6, out);
}

// Round 5
// 107.471 us; speedup vs baseline: 1.0543x; 1.0543x over previous
//
#include <hip/hip_runtime.h>
#include <hip/hip_bf16.h>

// CriticHead fused, round 5: single kernel, minimal serial latency chains.
//
// Math (verified R1 fp32 absmax 0; R2-R4 bf16 absmax 1.5 < 2.0):
//   feat[t] = [outer3(res,fr,estep)(150) | backbone(768)]  (W1 row order)
//   y2 = relu(feat @ W1 + b1);  y41 = y2*mean(enode);  y42 = y2*(sum ccl)(sum cnd)
//   heads -> y = (1-p)*(-100) + p*(y61+y62), p = sig(me*d3+b3)*sig(sc*d5+b5)
//
// R2/R3/R4 all land 105.9-113.3 despite different W1 paths -> kernel is
// latency/overhead bound, not pipe bound. R5 changes vs R4:
//  - all global reads (bb + outer factors) issued before any LDS write:
//    the two cold-HBM round trips overlap into one
//  - s_small + one __syncthreads removed (outer factors read via L1 directly)
//  - B gather uses a 4-slot rolling prefetch window (depth 3, ~32 VGPR)
//    instead of a 116-VGPR hoisted array -> no spill
// Values and op order identical to R2-R4 -> absmax stays exactly 1.5.

typedef __bf16  bf16x8 __attribute__((ext_vector_type(8)));
typedef float   f32x4  __attribute__((ext_vector_type(4)));
typedef unsigned int uintx4 __attribute__((ext_vector_type(4)));
typedef unsigned short ushort4e __attribute__((ext_vector_type(4)));

#define FAILC -100.0f
#define ASTRIDE 936         // LDS feat row stride in bf16 (16B-aligned rows)

static __device__ __forceinline__ unsigned short f2bf(float f) {
    unsigned u = __builtin_bit_cast(unsigned, f);
    u = (u + 0x7FFFu + ((u >> 16) & 1u)) >> 16;   // RNE
    return (unsigned short)u;
}

__global__ __launch_bounds__(512) void critic_fused(
    const float* __restrict__ bb,     // [T,768]
    const float* __restrict__ res,    // [T,5]
    const float* __restrict__ fr,     // [T,5]
    const float* __restrict__ estep,  // [T,6]
    const float* __restrict__ enode,  // [T,64]
    const float* __restrict__ ccl,    // [T,4]
    const float* __restrict__ cnd,    // [T,32]
    const float* __restrict__ W1,     // [918,128]
    const float* __restrict__ b1,     // [128]
    const float* __restrict__ W3, const float* __restrict__ b3,
    const float* __restrict__ W4, const float* __restrict__ b4,
    const float* __restrict__ W5, const float* __restrict__ b5,
    const float* __restrict__ W6, const float* __restrict__ b6,
    float* __restrict__ out)          // [T]
{
    __shared__ unsigned short a_lds[16 * ASTRIDE];  // bf16 feat, K-permuted
    __shared__ float s_y2[16][132];                 // relu(fc1) fp32

    const int t = threadIdx.x;
    const int task0 = blockIdx.x * 16;

    const int lane = t & 63;
    const int wave = t >> 6;
    const int mrow = lane & 15;
    const int quad = lane >> 4;
    const int ncol = wave * 16 + mrow;

    // ---- issue ALL global reads up front (overlap HBM round trips) ----
    const float4* bbp = (const float4*)(bb + (size_t)task0 * 768);
    float4 bbv[6];
#pragma unroll
    for (int it = 0; it < 6; ++it) bbv[it] = bbp[t + it * 512];

    // outer-product factors for this thread's (up to) 5 feature slots
    float ov0[5], ov1[5], ov2[5];
#pragma unroll
    for (int it = 0; it < 5; ++it) {
        int w = t + it * 512;                  // 0..2559
        if (w < 2400) {
            int r = w / 150;
            int idx = w - r * 150;
            int n = idx / 30;
            int rem = idx - n * 30;
            int m = rem / 6;
            int o = rem - m * 6;
            int tg = task0 + r;
            ov0[it] = res[tg * 5 + n];
            ov1[it] = fr[tg * 5 + m];
            ov2[it] = estep[tg * 6 + o];
        }
    }

    // ---- write backbone -> bf16 LDS cols [0,768) ----
#pragma unroll
    for (int it = 0; it < 6; ++it) {
        int i = t + it * 512;          // 0..3071
        int m = i / 192;               // task row
        int off = (i - m * 192) * 4;   // col in [0,768)
        float4 v = bbv[it];
        ushort4e pk = { f2bf(v.x), f2bf(v.y), f2bf(v.z), f2bf(v.w) };
        *(ushort4e*)&a_lds[m * ASTRIDE + off] = pk;
    }

    // outer products -> cols [768,918); zero pad cols [918,928)
#pragma unroll
    for (int it = 0; it < 5; ++it) {
        int w = t + it * 512;
        if (w < 2400) {
            int r = w / 150;
            int idx = w - r * 150;
            float v = ov0[it] * ov1[it] * ov2[it];
            a_lds[r * ASTRIDE + 768 + idx] = f2bf(v);
        } else {
            int z = w - 2400;              // 0..159
            int r = z / 10;
            a_lds[r * ASTRIDE + 918 + (z - r * 10)] = 0;
        }
    }
    __syncthreads();   // single pre-MFMA barrier

    // ---- MFMA loop: A from LDS, B gathered from W1 with rolling prefetch.
    // frag j of chunk c: B[k=32c+quad*8+j][ncol]; permuted K: k<768 -> row
    // 150+k, 768<=k<918 -> row k-768, else 0.
    const unsigned short* aptr = a_lds + mrow * ASTRIDE + quad * 8;

    float bw[4][8];    // 4-slot window, prefetch depth 3
#pragma unroll
    for (int c = 0; c < 3; ++c) {
        const int kq0 = c * 32 + quad * 8;
#pragma unroll
        for (int j = 0; j < 8; ++j) {
            int k = kq0 + j;
            int row = (k < 768) ? (150 + k) : (k - 768);
            bw[c][j] = (k < 918) ? W1[(size_t)row * 128 + ncol] : 0.0f;
        }
    }

    f32x4 acc = {0.f, 0.f, 0.f, 0.f};
#pragma unroll
    for (int c = 0; c < 29; ++c) {
        const int slot = c & 3;
        uintx4 bp;
        bp.x = (unsigned)f2bf(bw[slot][0]) | ((unsigned)f2bf(bw[slot][1]) << 16);
        bp.y = (unsigned)f2bf(bw[slot][2]) | ((unsigned)f2bf(bw[slot][3]) << 16);
        bp.z = (unsigned)f2bf(bw[slot][4]) | ((unsigned)f2bf(bw[slot][5]) << 16);
        bp.w = (unsigned)f2bf(bw[slot][6]) | ((unsigned)f2bf(bw[slot][7]) << 16);
        if (c + 3 < 29) {
            const int cn = c + 3;
            const int sn = cn & 3;
            const int kq0 = cn * 32 + quad * 8;
#pragma unroll
            for (int j = 0; j < 8; ++j) {
                int k = kq0 + j;
                int row = (k < 768) ? (150 + k) : (k - 768);
                bw[sn][j] = (k < 918) ? W1[(size_t)row * 128 + ncol] : 0.0f;
            }
        }
        uintx4 au = *(const uintx4*)(aptr + c * 32);
        acc = __builtin_amdgcn_mfma_f32_16x16x32_bf16(
            __builtin_bit_cast(bf16x8, au), __builtin_bit_cast(bf16x8, bp),
            acc, 0, 0, 0);
    }

    // epilogue: bias + relu -> s_y2.  D layout: col=lane&15, row=quad*4+reg.
    {
        float bias = b1[ncol];
#pragma unroll
        for (int r = 0; r < 4; ++r) {
            int m = quad * 4 + r;
            s_y2[m][ncol] = fmaxf(acc[r] + bias, 0.f);
        }
    }
    __syncthreads();

    // ---- heads (identical math to R1-R4) ----
    const int kq = t & 31;
    const int rsub = t >> 5;
    const int tg = task0 + rsub;
    const int k4 = kq * 4;

    float4 yv = *(const float4*)&s_y2[rsub][k4];
    float y0 = yv.x, y1 = yv.y, y2v = yv.z, y3 = yv.w;

    float4 w3v = *(const float4*)(W3 + k4);
    float4 w4v = *(const float4*)(W4 + k4);
    float4 w5v = *(const float4*)(W5 + k4);
    float4 w6v = *(const float4*)(W6 + k4);
    float pd3 = y0 * w3v.x + y1 * w3v.y + y2v * w3v.z + y3 * w3v.w;
    float pd4 = y0 * w4v.x + y1 * w4v.y + y2v * w4v.z + y3 * w4v.w;
    float pd5 = y0 * w5v.x + y1 * w5v.y + y2v * w5v.z + y3 * w5v.w;
    float pd6 = y0 * w6v.x + y1 * w6v.y + y2v * w6v.z + y3 * w6v.w;

    const float* en = enode + (size_t)tg * 64 + kq * 2;
    float pe = en[0] + en[1];
    float pc = (kq < 4) ? ccl[tg * 4 + kq] : 0.f;
    float pn = cnd[tg * 32 + kq];

#pragma unroll
    for (int m = 1; m < 32; m <<= 1) {
        pd3 += __shfl_xor(pd3, m);
        pd4 += __shfl_xor(pd4, m);
        pd5 += __shfl_xor(pd5, m);
        pd6 += __shfl_xor(pd6, m);
        pe  += __shfl_xor(pe, m);
        pc  += __shfl_xor(pc, m);
        pn  += __shfl_xor(pn, m);
    }

    if (kq == 0) {
        float me = pe * (1.0f / 64.0f);
        float sc = pc * pn;
        float a3 = me * pd3 + b3[0];
        float a5 = sc * pd5 + b5[0];
        float y51 = 1.0f / (1.0f + __expf(-a3));
        float y52 = 1.0f / (1.0f + __expf(-a5));
        float y61 = me * pd4 + b4[0];
        float y62 = sc * pd6 + b6[0];
        float p = y51 * y52;
        out[tg] = (1.0f - p) * FAILC + p * (y61 + y62);
    }
}

extern "C" void kernel_launch(void* const* d_in, const int* in_sizes, int n_in,
                              void* d_out, int out_size, void* d_ws, size_t ws_size,
                              hipStream_t stream) {
    const float* bb    = (const float*)d_in[2];
    const float* res   = (const float*)d_in[3];
    const float* fr    = (const float*)d_in[4];
    const float* estep = (const float*)d_in[5];
    const float* enode = (const float*)d_in[6];
    const float* ccl   = (const float*)d_in[7];
    const float* cnd   = (const float*)d_in[8];
    const float* W1    = (const float*)d_in[9];
    const float* b1    = (const float*)d_in[10];
    const float* W3    = (const float*)d_in[11];
    const float* b3    = (const float*)d_in[12];
    const float* W4    = (const float*)d_in[13];
    const float* b4    = (const float*)d_in[14];
    const float* W5    = (const float*)d_in[15];
    const float* b5    = (const float*)d_in[16];
    const float* W6    = (const float*)d_in[17];
    const float* b6    = (const float*)d_in[18];
    float* out = (float*)d_out;

    int T = in_sizes[3] / 5;      // y_res is [T,5]
    int blocks = T / 16;          // 16 tasks per block

    hipLaunchKernelGGL(critic_fused, dim3(blocks), dim3(512), 0, stream,
                       bb, res, fr, estep, enode, ccl, cnd,
                       W1, b1, W3, b3, W4, b4, W5, b5, W6, b6, out);
}